// Round 2
// baseline (306.178 us; speedup 1.0000x reference)
//
#include <hip/hip_runtime.h>
#include <hip/hip_bf16.h>

#define B_ 8
#define N_ 2048
#define D_ 64

typedef __attribute__((ext_vector_type(8))) short bf16x8;
typedef __attribute__((ext_vector_type(4))) float f32x4;

__device__ inline unsigned short f32_bf16_rne(float f) {
    unsigned u = __float_as_uint(f);
    u += 0x7fffu + ((u >> 16) & 1u);
    return (unsigned short)(u >> 16);
}

// Kernel A: h = feats @ W^T (fp32), a_src/a_dst reductions, store hT[b][d][j] as bf16.
// 512 blocks x 256 threads; each block does 32 rows of one batch.
__global__ __launch_bounds__(256) void prep_kernel(
    const float* __restrict__ feats, const float* __restrict__ W,
    const float* __restrict__ attn_src, const float* __restrict__ attn_dst,
    unsigned short* __restrict__ hT, float* __restrict__ a_src,
    float* __restrict__ a_dst) {
    __shared__ float w_lds[64 * 65];          // padded: bank = (o+d)%32, conflict-free
    __shared__ float f_lds[32 * 64];
    __shared__ unsigned short hT_lds[64 * 40]; // row stride 40 ushorts = 80B (16B aligned)

    const int t = threadIdx.x;
    const int b = blockIdx.x >> 6;            // 64 row-tiles per batch
    const int rowbase = (blockIdx.x & 63) * 32;

    // cooperative load W (64x64) into padded LDS
#pragma unroll
    for (int k = 0; k < 4; k++) {
        int lin = (k * 256 + t) * 4;
        float4 v = *(const float4*)(W + lin);
        int o = lin >> 6, d = lin & 63;
        float* p = &w_lds[o * 65 + d];
        p[0] = v.x; p[1] = v.y; p[2] = v.z; p[3] = v.w;
    }
    // cooperative load feats tile (32x64), linear layout
#pragma unroll
    for (int k = 0; k < 2; k++) {
        int lin = (k * 256 + t) * 4;
        float4 v = *(const float4*)(feats + (size_t)(b * N_ + rowbase) * D_ + lin);
        float* p = &f_lds[lin];
        p[0] = v.x; p[1] = v.y; p[2] = v.z; p[3] = v.w;
    }
    __syncthreads();

    const int w = t >> 6;     // wave id: rows w*8 .. w*8+7
    const int o = t & 63;     // output channel
    float acc[8] = {0.f, 0.f, 0.f, 0.f, 0.f, 0.f, 0.f, 0.f};
#pragma unroll 8
    for (int d = 0; d < 64; d++) {
        float wv = w_lds[o * 65 + d];
#pragma unroll
        for (int rr = 0; rr < 8; rr++)
            acc[rr] = fmaf(f_lds[(w * 8 + rr) * 64 + d], wv, acc[rr]);
    }
    float as_ = attn_src[o], ad_ = attn_dst[o];
#pragma unroll
    for (int rr = 0; rr < 8; rr++) {
        int row = rowbase + w * 8 + rr;
        float s1 = acc[rr] * as_;
        float s2 = acc[rr] * ad_;
#pragma unroll
        for (int off = 32; off; off >>= 1) {
            s1 += __shfl_xor(s1, off);
            s2 += __shfl_xor(s2, off);
        }
        if (o == 0) {
            a_src[b * N_ + row] = s1;
            a_dst[b * N_ + row] = s2;
        }
        hT_lds[o * 40 + w * 8 + rr] = f32_bf16_rne(acc[rr]);
    }
    __syncthreads();
    // transposed store: hT[b][d][rowbase..rowbase+32)
    const int d = t >> 2, seg = t & 3;
    uint4 vv = *(const uint4*)(&hT_lds[d * 40 + seg * 8]);
    *(uint4*)(hT + ((size_t)(b * 64 + d) * N_ + rowbase + seg * 8)) = vv;
}

// Kernel B: masked dual-softmax attention via bf16 MFMA, single pass (no online max).
// 256 blocks x 256 threads; block = 64 rows of one batch (4 waves x 16 rows).
__global__ __launch_bounds__(256) void attn_kernel(
    const int* __restrict__ mask_adj, const int* __restrict__ mask_job,
    const int* __restrict__ batch_idxes,
    const unsigned short* __restrict__ hT, const float* __restrict__ a_src,
    const float* __restrict__ a_dst, const float* __restrict__ feats,
    const float* __restrict__ lambda_params, float* __restrict__ out) {
    // hT tile staged XOR-swizzled in 16B chunks: row d, logical chunk jc at
    // physical chunk (jc ^ (d&15)). 64 d x 128 j bf16 = 16 KB.
    __shared__ unsigned short hstage[64 * 128];

    const int t = threadIdx.x;
    const int b = blockIdx.x >> 5;            // 32 blocks per batch
    const int ibase = (blockIdx.x & 31) * 64;
    const int wid = t >> 6, lane = t & 63;
    const int m = lane & 15, q = lane >> 4;
    const int irow0 = ibase + wid * 16;
    const int i_a = irow0 + m;                // A-fragment row this lane owns

    // harness materializes integer inputs as int32; clamp so a bad value can
    // never fault (reference batch_idxes is arange(B))
    int bi = batch_idxes[b];
    bi = (bi < 0) ? 0 : ((bi >= B_) ? (B_ - 1) : bi);
    const int* mA = mask_adj + (size_t)bi * N_ * N_ + (size_t)i_a * N_;
    const int* mJ = mask_job + (size_t)bi * N_ * N_ + (size_t)i_a * N_;
    const float asrc = a_src[b * N_ + i_a];
    const float* adst = a_dst + b * N_;

    f32x4 accA[4], accJ[4];
#pragma unroll
    for (int dd = 0; dd < 4; dd++) {
        accA[dd] = (f32x4){0.f, 0.f, 0.f, 0.f};
        accJ[dd] = (f32x4){0.f, 0.f, 0.f, 0.f};
    }
    float zA = 0.f, zJ = 0.f;

    const int sd = t >> 2, sseg = t & 3;      // staging role: row d, 4-chunk segment
    const unsigned short* hrow = hT + (size_t)(b * 64 + sd) * N_;

    for (int jt = 0; jt < N_ / 128; jt++) {
        const int j0 = jt * 128;
        // stage hT[b][*][j0..j0+128) into swizzled LDS
#pragma unroll
        for (int c = 0; c < 4; c++) {
            int jc = sseg * 4 + c;
            uint4 v = *(const uint4*)(hrow + j0 + jc * 8);
            *(uint4*)(hstage + (sd * 16 + (jc ^ (sd & 15))) * 8) = v;
        }
        __syncthreads();

#pragma unroll
        for (int kk = 0; kk < 4; kk++) {
            const int jl = j0 + kk * 32 + q * 8;  // this lane's 8 k-slots
            int4 a0 = *(const int4*)(mA + jl);
            int4 a1 = *(const int4*)(mA + jl + 4);
            int4 b0 = *(const int4*)(mJ + jl);
            int4 b1 = *(const int4*)(mJ + jl + 4);
            float4 d0 = *(const float4*)(adst + jl);
            float4 d1 = *(const float4*)(adst + jl + 4);
            int ma[8] = {a0.x, a0.y, a0.z, a0.w, a1.x, a1.y, a1.z, a1.w};
            int mj[8] = {b0.x, b0.y, b0.z, b0.w, b1.x, b1.y, b1.z, b1.w};
            float dv[8] = {d0.x, d0.y, d0.z, d0.w, d1.x, d1.y, d1.z, d1.w};
            bf16x8 fa, fj;
#pragma unroll
            for (int tt = 0; tt < 8; tt++) {
                float e = asrc + dv[tt];
                float le = fmaxf(e, 0.f) + 0.2f * fminf(e, 0.f);
                float p = __expf(le);          // no max-sub needed: e <= ~9
                float pa = (ma[tt] == 1) ? p : 0.f;
                float pj = (mj[tt] == 1) ? p : 0.f;
                zA += pa;
                zJ += pj;
                fa[tt] = (short)f32_bf16_rne(pa);
                fj[tt] = (short)f32_bf16_rne(pj);
            }
#pragma unroll
            for (int dd = 0; dd < 4; dd++) {
                int dn = dd * 16 + m;
                int jcl = kk * 4 + q;
                bf16x8 fb = *(const bf16x8*)(hstage +
                                (dn * 16 + (jcl ^ (dn & 15))) * 8);
                accA[dd] = __builtin_amdgcn_mfma_f32_16x16x32_bf16(fa, fb, accA[dd], 0, 0, 0);
                accJ[dd] = __builtin_amdgcn_mfma_f32_16x16x32_bf16(fj, fb, accJ[dd], 0, 0, 0);
            }
        }
        __syncthreads();
    }

    // finish Z: sum the 4 q-partials per row
    zA += __shfl_xor(zA, 16); zA += __shfl_xor(zA, 32);
    zJ += __shfl_xor(zJ, 16); zJ += __shfl_xor(zJ, 32);
    float* zbuf = (float*)hstage;             // all waves done with hstage
    if (q == 0) {
        zbuf[wid * 32 + m] = zA;
        zbuf[wid * 32 + 16 + m] = zJ;
    }
    __syncthreads();

    float invA[4], invJ[4];
#pragma unroll
    for (int r = 0; r < 4; r++) {
        invA[r] = 1.f / zbuf[wid * 32 + q * 4 + r];
        invJ[r] = 1.f / zbuf[wid * 32 + 16 + q * 4 + r];
    }
#pragma unroll
    for (int dd = 0; dd < 4; dd++) {
        int d = dd * 16 + m;                  // C-frag col = lane&15
        float l0 = lambda_params[d * 2];
        float l1 = lambda_params[d * 2 + 1];
        float e0 = __expf(l0), e1 = __expf(l1);
        float inv = 1.f / (e0 + e1);
        float la = e0 * inv, lj = e1 * inv;
#pragma unroll
        for (int r = 0; r < 4; r++) {
            int i = irow0 + q * 4 + r;        // C-frag row = quad*4 + reg
            size_t off = (size_t)(b * N_ + i) * D_ + d;
            out[off] = la * accA[dd][r] * invA[r] + lj * accJ[dd][r] * invJ[r] + feats[off];
        }
    }
}

extern "C" void kernel_launch(void* const* d_in, const int* in_sizes, int n_in,
                              void* d_out, int out_size, void* d_ws, size_t ws_size,
                              hipStream_t stream) {
    const int* mask_adj = (const int*)d_in[0];
    const int* mask_job = (const int*)d_in[1];
    const int* batch_idxes = (const int*)d_in[2];
    const float* feats = (const float*)d_in[3];
    const float* W = (const float*)d_in[4];
    const float* attn_src = (const float*)d_in[5];
    const float* attn_dst = (const float*)d_in[6];
    const float* lambda_params = (const float*)d_in[7];
    float* out = (float*)d_out;

    unsigned short* hT = (unsigned short*)d_ws;                     // B*64*N bf16 = 2 MB
    float* a_src = (float*)((char*)d_ws + (size_t)B_ * 64 * N_ * 2);
    float* a_dst = a_src + B_ * N_;

    prep_kernel<<<B_ * (N_ / 32), 256, 0, stream>>>(feats, W, attn_src, attn_dst,
                                                    hT, a_src, a_dst);
    attn_kernel<<<B_ * (N_ / 64), 256, 0, stream>>>(mask_adj, mask_job, batch_idxes,
                                                    hT, a_src, a_dst, feats,
                                                    lambda_params, out);
}